// Round 11
// baseline (371.440 us; speedup 1.0000x reference)
//
#include <hip/hip_runtime.h>

#define NNODES 10000
#define NEDGES 160000
#define MPAD   10240      // 40 * 256
#define FIN    768
#define D2     1024
#define D2X2   2048
#define TSTEPS 50
#define LDSB   131072     // gemm8p: 2 slots x (A 32KB + B 32KB)

typedef __bf16 bf16x8 __attribute__((ext_vector_type(8)));
typedef float  f32x4  __attribute__((ext_vector_type(4)));
typedef float  f32x2  __attribute__((ext_vector_type(2)));

__device__ __forceinline__ unsigned short f2bf(float f) {
    unsigned u = __builtin_bit_cast(unsigned, f);
    u += 0x7FFFu + ((u >> 16) & 1u);
    return (unsigned short)(u >> 16);
}
__device__ __forceinline__ f32x2 unpk2(unsigned u) {
    f32x2 r;
    r.x = __builtin_bit_cast(float, u << 16);
    r.y = __builtin_bit_cast(float, u & 0xFFFF0000u);
    return r;
}
__device__ __forceinline__ void gload16(const void* g, void* l) {
    __builtin_amdgcn_global_load_lds((const __attribute__((address_space(1))) void*)g,
                                     (__attribute__((address_space(3))) void*)l, 16, 0, 0);
}

// ---------------- CSR: count ----------------
__global__ void csr_count(const int* __restrict__ ei, int* cnt) {
    int g = blockIdx.x * 256 + threadIdx.x;
    if (g < NEDGES) atomicAdd(&cnt[ei[NEDGES + g]], 1);
}
// ---------------- CSR: scan (+ cosine schedule fold-in) ----------------
__global__ void csr_scan(const int* __restrict__ cnt, int* rowp, int* cur, float* sched) {
    if (threadIdx.x == 0) {
        const double PI = 3.14159265358979323846;
        double acp = 1.0;
        for (int i = 0; i < TSTEPS; ++i) {
            double x0 = (double)i / (double)TSTEPS;
            double x1 = (double)(i + 1) / (double)TSTEPS;
            double c0 = cos((x0 + 0.008) / 1.008 * PI * 0.5);
            double c1 = cos((x1 + 0.008) / 1.008 * PI * 0.5);
            double a0 = c0 * c0, a1 = c1 * c1;
            double beta = 1.0 - a1 / a0;
            if (beta < 0.0) beta = 0.0;
            if (beta > 0.999) beta = 0.999;
            acp *= (1.0 - beta);
            sched[i]      = (float)sqrt(acp);
            sched[64 + i] = (float)sqrt(1.0 - acp);
        }
    }
    __shared__ int part[1024];
    int tid = threadIdx.x;
    const int per = 10;
    int base = tid * per;
    int local[per];
    int s = 0;
    #pragma unroll
    for (int i = 0; i < per; ++i) {
        int idx = base + i;
        int v = (idx < NNODES) ? (cnt[idx] + 1) : 0;   // +1 = self loop
        local[i] = s;
        s += v;
    }
    part[tid] = s;
    __syncthreads();
    for (int off = 1; off < 1024; off <<= 1) {
        int v = (tid >= off) ? part[tid - off] : 0;
        __syncthreads();
        part[tid] += v;
        __syncthreads();
    }
    int offset = (tid > 0) ? part[tid - 1] : 0;
    #pragma unroll
    for (int i = 0; i < per; ++i) {
        int idx = base + i;
        if (idx < NNODES) {
            int v = offset + local[i];
            rowp[idx] = v;
            cur[idx]  = v;
        } else if (idx == NNODES) {
            rowp[NNODES] = offset + local[i];
        }
    }
}
// ---------------- CSR: fill (self loop at fixed last slot) ----------------
__global__ void csr_fill(const int* __restrict__ ei, const int* __restrict__ rowp,
                         int* cur, int* colv) {
    int g = blockIdx.x * 256 + threadIdx.x;
    if (g < NEDGES) {
        int s = ei[g];
        int d = ei[NEDGES + g];
        int pos = atomicAdd(&cur[d], 1);
        colv[pos] = s;
    } else if (g < NEDGES + NNODES) {
        int d = g - NEDGES;
        colv[rowp[d + 1] - 1] = d;
    }
}

// ---------------- unified weight transpose: 5 jobs, fp32 [K][N] -> bf16 [N][K] ----------------
struct TJ { const float* W; unsigned short* out; int K; int N; int end; };
struct TJ5 { TJ j[5]; };
__global__ void __launch_bounds__(256)
prep_all(TJ5 js) {
    int b = blockIdx.x;
    int i = 0;
    #pragma unroll
    for (int k = 0; k < 5; ++k) if (b >= js.j[k].end) i = k + 1;
    TJ p = js.j[i];
    int start = (i > 0) ? js.j[i - 1].end : 0;
    int lt = b - start;
    int kt = p.K >> 5;                 // tiles along K
    int kb = (lt % kt) * 32;
    int nb = (lt / kt) * 32;
    __shared__ float tile[32][33];
    const int tx = threadIdx.x & 31, ty = threadIdx.x >> 5;   // ty 0..7
    #pragma unroll
    for (int r = 0; r < 32; r += 8)
        tile[ty + r][tx] = p.W[(size_t)(kb + ty + r) * p.N + nb + tx];   // coalesced read
    __syncthreads();
    #pragma unroll
    for (int r = 0; r < 32; r += 8)
        p.out[(size_t)(nb + ty + r) * p.K + kb + tx] = f2bf(tile[tx][ty + r]);  // coalesced write
}

// ---------------- diffusion noise add -> bf16 ----------------
__global__ void x0_kernel(const float* __restrict__ emb, const float* __restrict__ noise,
                          const int* __restrict__ t, const float* __restrict__ sched,
                          unsigned short* __restrict__ x0b) {
    int i4 = blockIdx.x * 256 + threadIdx.x;
    if (i4 >= MPAD * (FIN / 4)) return;
    int row = i4 / (FIN / 4);
    int c = (i4 % (FIN / 4)) * 4;
    unsigned short* dst = x0b + (size_t)row * FIN + c;
    if (row < NNODES) {
        int tv = t[row];
        float sa = sched[tv], so = sched[64 + tv];
        float4 e = *(const float4*)(emb + (size_t)row * FIN + c);
        float4 nz = *(const float4*)(noise + (size_t)row * FIN + c);
        float v0 = sa * e.x + so * nz.x;
        float v1 = sa * e.y + so * nz.y;
        float v2 = sa * e.z + so * nz.z;
        float v3 = sa * e.w + so * nz.w;
        uint2 pk;
        pk.x = (unsigned)f2bf(v0) | ((unsigned)f2bf(v1) << 16);
        pk.y = (unsigned)f2bf(v2) | ((unsigned)f2bf(v3) << 16);
        *(uint2*)dst = pk;
    } else {
        uint2 pk; pk.x = 0u; pk.y = 0u;
        *(uint2*)dst = pk;
    }
}

// ---------------- 256x256 counted-vmcnt 4-phase GEMM (bf16 out) ----------------
// C[M][Nn] = A[M][K] @ Bt[Nn][K]^T + bias.  512 thr = 8 waves (2M x 4N), wave tile 128x64.
// 2-slot LDS dbuf (128 KB). Per K-tile: 8 staging units of 64 rows, per-thread issue order
// [B0,B1,B2,B3,A0,A2,A1,A3]; phase (mh,ks) needs A-unit 2*wm+mh + all B.
// Ledger (per thread, steady state; outstanding at gate-A = tile t's 8 units):
//   gate-A: vmcnt(2)+barrier  -> B0..B3,A0,A2 landed (A1,A3 may fly)
//   ph0/ph1 (mh=0) compute; issue next tile's B0,B1 / B2,B3  (outstanding <= 6)
//   gate-B: vmcnt(4)+barrier  -> A1,A3 landed (only next tile's B units fly)
//   ph2/ph3 (mh=1) compute; issue next tile's A0,A2 / A1,A3  (outstanding <= 8)
// Last tile stages nothing; gate-B becomes vmcnt(0). Slot t&1 is overwritten only by
// stage(t+2) issued after the NEXT gate-A barrier, which every wave reaches only after
// its tile-t ds_reads retired (lgkmcnt before MFMA) -> no LDS race.
__global__ void __launch_bounds__(512, 1)
gemm8p(const unsigned short* __restrict__ A, const unsigned short* __restrict__ Bt,
       const float* __restrict__ bl, const float* __restrict__ br, void* __restrict__ C,
       int K, int Nn, int gy) {
    extern __shared__ char lds[];
    const int tid = threadIdx.x;
    const int lane = tid & 63;
    const int wv = tid >> 6;          // 0..7
    const int wm = wv >> 2;           // 0..1 : 128-row half
    const int wn = wv & 3;            // 0..3 : 64-col quarter
    const int lr = lane & 15;
    const int kq = lane >> 4;

    // T1: bijective XCD swizzle (m204)
    const int total = gridDim.x;
    int lin = blockIdx.x;
    int q = total >> 3, r = total & 7;
    int xcd = lin & 7, idx = lin >> 3;
    int lin2 = (xcd < r ? xcd * (q + 1) : r * (q + 1) + (xcd - r) * q) + idx;
    const int rowBase = (lin2 / gy) * 256;
    const int colBase = (lin2 % gy) * 256;

    f32x4 acc[8][4];
    #pragma unroll
    for (int m = 0; m < 8; ++m)
        #pragma unroll
        for (int n = 0; n < 4; ++n)
            acc[m][n] = (f32x4){0.f, 0.f, 0.f, 0.f};

    const int r8 = tid >> 3;          // 0..63
    const int cb = (tid & 7) * 16;    // byte col in 128B row
    const size_t Kb = (size_t)K * 2;
    const int NT = K >> 6;

    // staging unit j (64 rows starting j*64); dest linear in tid (wave-uniform + lane*16)
    auto issueA = [&](char* dst, int j, int kt) {
        int row = j * 64 + r8;
        int scb = cb ^ ((row & 7) << 4);                 // inverse-swizzled global source
        gload16((const char*)A + (size_t)(rowBase + row) * Kb + (size_t)kt * 2 + scb,
                dst + row * 128 + cb);
    };
    auto issueB = [&](char* dst, int j, int kt) {
        int row = j * 64 + r8;
        int scb = cb ^ ((row & 7) << 4);
        gload16((const char*)Bt + (size_t)(colBase + row) * Kb + (size_t)kt * 2 + scb,
                dst + 32768 + row * 128 + cb);
    };

    // prologue: stage tile 0 into slot 0, order B0..B3, A0, A2, A1, A3
    {
        char* d0 = lds;
        issueB(d0, 0, 0); issueB(d0, 1, 0); issueB(d0, 2, 0); issueB(d0, 3, 0);
        issueA(d0, 0, 0); issueA(d0, 2, 0); issueA(d0, 1, 0); issueA(d0, 3, 0);
    }

#define GPHASE(MH, KS, STG) {                                                              \
        bf16x8 fa[4], fb[4];                                                               \
        _Pragma("unroll")                                                                  \
        for (int m = 0; m < 4; ++m) {                                                      \
            int fr = wm * 128 + ((MH) * 4 + m) * 16 + lr;                                  \
            fa[m] = *(const bf16x8*)(la + ((fr * 128 + (KS) * 64 + kq * 16) ^ ((fr & 7) << 4))); \
        }                                                                                  \
        _Pragma("unroll")                                                                  \
        for (int n = 0; n < 4; ++n) {                                                      \
            int fr = wn * 64 + n * 16 + lr;                                                \
            fb[n] = *(const bf16x8*)(lb + ((fr * 128 + (KS) * 64 + kq * 16) ^ ((fr & 7) << 4))); \
        }                                                                                  \
        STG;                                                                               \
        __builtin_amdgcn_sched_barrier(0);                                                 \
        __builtin_amdgcn_s_setprio(1);                                                     \
        _Pragma("unroll")                                                                  \
        for (int m = 0; m < 4; ++m)                                                        \
            _Pragma("unroll")                                                              \
            for (int n = 0; n < 4; ++n)                                                    \
                acc[(MH) * 4 + m][n] =                                                     \
                    __builtin_amdgcn_mfma_f32_16x16x32_bf16(fa[m], fb[n], acc[(MH) * 4 + m][n], 0, 0, 0); \
        __builtin_amdgcn_s_setprio(0);                                                     \
        __builtin_amdgcn_sched_barrier(0);                                                 \
        __builtin_amdgcn_s_barrier();                                                      \
    }

    for (int t = 0; t < NT; ++t) {
        // gate A: tile t's B0..B3,A0,A2 landed in all threads' view
        asm volatile("s_waitcnt vmcnt(2)" ::: "memory");
        __builtin_amdgcn_s_barrier();
        const char* la = lds + (t & 1) * 65536;
        const char* lb = la + 32768;
        char* dn = lds + ((t + 1) & 1) * 65536;
        const bool st = (t + 1 < NT);
        const int kt1 = (t + 1) << 6;

        GPHASE(0, 0, { if (st) { issueB(dn, 0, kt1); issueB(dn, 1, kt1); } })
        GPHASE(0, 1, { if (st) { issueB(dn, 2, kt1); issueB(dn, 3, kt1); } })

        // gate B: tile t's A1,A3 landed (next tile's B units may fly)
        if (st) asm volatile("s_waitcnt vmcnt(4)" ::: "memory");
        else    asm volatile("s_waitcnt vmcnt(0)" ::: "memory");
        __builtin_amdgcn_s_barrier();

        GPHASE(1, 0, { if (st) { issueA(dn, 0, kt1); issueA(dn, 2, kt1); } })
        GPHASE(1, 1, { if (st) { issueA(dn, 1, kt1); issueA(dn, 3, kt1); } })
    }
#undef GPHASE

    // epilogue: col = lane&15, row = kq*4 + j; bias two-pointer
    #pragma unroll
    for (int n = 0; n < 4; ++n) {
        int col = colBase + wn * 64 + n * 16 + lr;
        float bcol = (col < D2) ? bl[col] : br[col - D2];
        #pragma unroll
        for (int m = 0; m < 8; ++m) {
            int row0 = rowBase + wm * 128 + m * 16 + kq * 4;
            #pragma unroll
            for (int j = 0; j < 4; ++j) {
                float v = acc[m][n][j] + bcol;
                ((unsigned short*)C)[(size_t)(row0 + j) * Nn + col] = f2bf(v);
            }
        }
    }
}

// ---------------- m97-style bf16 MFMA GEMM (round-7 proven; used for out-GEMM) ----------------
template<bool OUT_BF16>
__global__ void __launch_bounds__(256)
gemmM(const unsigned short* __restrict__ A, const unsigned short* __restrict__ Bt,
      const float* __restrict__ bl, const float* __restrict__ br, void* __restrict__ C,
      int K, int Nn, int Mstore, int gy) {
    __shared__ __align__(16) unsigned short As[128 * 64];   // 16 KB
    __shared__ __align__(16) unsigned short Bs[128 * 64];   // 16 KB

    const int tid = threadIdx.x;
    const int lane = tid & 63;
    const int wv = tid >> 6;          // 0..3
    const int wm = wv >> 1;           // 0..1
    const int wn = wv & 1;            // 0..1
    const int lr = lane & 15;
    const int kq = lane >> 4;

    const int total = gridDim.x;
    int lin = blockIdx.x;
    int q = total >> 3, r = total & 7;
    int xcd = lin & 7, idx = lin >> 3;
    int lin2 = (xcd < r ? xcd * (q + 1) : r * (q + 1) + (xcd - r) * q) + idx;
    const int rowBase = (lin2 / gy) * 128;
    const int colBase = (lin2 % gy) * 128;

    f32x4 acc[4][4];
    #pragma unroll
    for (int m = 0; m < 4; ++m)
        #pragma unroll
        for (int n = 0; n < 4; ++n)
            acc[m][n] = (f32x4){0.f, 0.f, 0.f, 0.f};

    const int r8 = tid >> 3;          // 0..31
    const int cb = (tid & 7) * 16;    // byte col in 128B row
    const size_t Kb = (size_t)K * 2;
    const int NT = K >> 6;

    for (int t = 0; t < NT; ++t) {
        const size_t kOff = (size_t)(t * 64) * 2;
        #pragma unroll
        for (int i = 0; i < 4; ++i) {
            int rr = i * 32 + r8;
            int scb = cb ^ ((rr & 7) << 4);     // inverse-swizzled global source
            gload16((const char*)A + (size_t)(rowBase + rr) * Kb + kOff + scb,
                    (char*)As + rr * 128 + cb);
            gload16((const char*)Bt + (size_t)(colBase + rr) * Kb + kOff + scb,
                    (char*)Bs + rr * 128 + cb);
        }
        __syncthreads();

        #pragma unroll
        for (int k2 = 0; k2 < 2; ++k2) {
            bf16x8 fa[4], fb[4];
            #pragma unroll
            for (int m = 0; m < 4; ++m) {
                int fr = wm * 64 + m * 16 + lr;
                int off = (fr * 128 + k2 * 64 + kq * 16) ^ ((fr & 7) << 4);  // T2 swizzled read
                fa[m] = *(const bf16x8*)((const char*)As + off);
            }
            #pragma unroll
            for (int n = 0; n < 4; ++n) {
                int fr = wn * 64 + n * 16 + lr;
                int off = (fr * 128 + k2 * 64 + kq * 16) ^ ((fr & 7) << 4);
                fb[n] = *(const bf16x8*)((const char*)Bs + off);
            }
            __builtin_amdgcn_s_setprio(1);
            #pragma unroll
            for (int m = 0; m < 4; ++m)
                #pragma unroll
                for (int n = 0; n < 4; ++n)
                    acc[m][n] = __builtin_amdgcn_mfma_f32_16x16x32_bf16(fa[m], fb[n], acc[m][n], 0, 0, 0);
            __builtin_amdgcn_s_setprio(0);
        }
        __syncthreads();
    }

    #pragma unroll
    for (int n = 0; n < 4; ++n) {
        int col = colBase + wn * 64 + n * 16 + lr;
        float bcol = (col < D2) ? bl[col] : br[col - D2];
        #pragma unroll
        for (int m = 0; m < 4; ++m) {
            int row0 = rowBase + wm * 64 + m * 16 + kq * 4;
            #pragma unroll
            for (int j = 0; j < 4; ++j) {
                float v = acc[m][n][j] + bcol;
                if (OUT_BF16) {
                    ((unsigned short*)C)[(size_t)(row0 + j) * Nn + col] = f2bf(v);
                } else {
                    if (row0 + j < Mstore)
                        ((float*)C)[(size_t)(row0 + j) * Nn + col] = v;
                }
            }
        }
    }
}

// ---------------- GATv2 attention: one wave per destination node (round-6/7/10 proven) ----------------
__global__ void __launch_bounds__(256)
attn_kernel(const unsigned short* __restrict__ xlr,
            const int* __restrict__ rowp, const int* __restrict__ colv,
            const float* __restrict__ att, const float* __restrict__ bias,
            unsigned short* __restrict__ out) {
    const int lane = threadIdx.x & 63;
    const int node = blockIdx.x * 4 + (threadIdx.x >> 6);
    const int j0 = lane * 16;

    if (node >= NNODES) {
        if (node < MPAD) {
            uint4 z; z.x = z.y = z.z = z.w = 0u;
            *(uint4*)(out + (size_t)node * D2 + j0) = z;
            *(uint4*)(out + (size_t)node * D2 + j0 + 8) = z;
        }
        return;
    }

    f32x2 attv[8], xrv[8], acc[8];
    #pragma unroll
    for (int q = 0; q < 8; ++q) attv[q] = *(const f32x2*)(att + j0 + 2 * q);
    {
        const unsigned short* xr = xlr + (size_t)node * D2X2 + D2 + j0;
        uint4 v0 = *(const uint4*)(xr);
        uint4 v1 = *(const uint4*)(xr + 8);
        unsigned u[8] = {v0.x, v0.y, v0.z, v0.w, v1.x, v1.y, v1.z, v1.w};
        #pragma unroll
        for (int q = 0; q < 8; ++q) xrv[q] = unpk2(u[q]);
    }
    #pragma unroll
    for (int q = 0; q < 8; ++q) acc[q] = (f32x2){0.f, 0.f};

    float mbase = 8.0f;     // fixed softmax base; rescale fallback keeps exactness
    float lsum = 0.f;

    const int p0 = rowp[node], p1 = rowp[node + 1];
    const int deg = p1 - p0;
    const int ngroups = deg >> 2;

    uint4 curA[4], curB[4];
    if (ngroups > 0) {
        #pragma unroll
        for (int i = 0; i < 4; ++i) {
            int s = colv[p0 + i];
            const unsigned short* src = xlr + (size_t)s * D2X2 + j0;
            curA[i] = *(const uint4*)src;
            curB[i] = *(const uint4*)(src + 8);
        }
    }

    for (int g = 0; g < ngroups; ++g) {
        uint4 nxtA[4], nxtB[4];
        const bool more = (g + 1 < ngroups);
        if (more) {
            int base = p0 + (g + 1) * 4;
            #pragma unroll
            for (int i = 0; i < 4; ++i) {
                int s = colv[base + i];
                const unsigned short* src = xlr + (size_t)s * D2X2 + j0;
                nxtA[i] = *(const uint4*)src;
                nxtB[i] = *(const uint4*)(src + 8);
            }
        }

        float part[4];
        #pragma unroll
        for (int e = 0; e < 4; ++e) {
            unsigned uw[8] = {curA[e].x, curA[e].y, curA[e].z, curA[e].w,
                              curB[e].x, curB[e].y, curB[e].z, curB[e].w};
            f32x2 d2 = (f32x2){0.f, 0.f};
            #pragma unroll
            for (int q = 0; q < 8; ++q) {
                f32x2 s = unpk2(uw[q]) + xrv[q];
                f32x2 t = s * 0.2f;
                s.x = fmaxf(s.x, t.x);
                s.y = fmaxf(s.y, t.y);
                d2 += s * attv[q];
            }
            float pt = d2.x + d2.y;
            pt += __shfl_xor(pt, 1);
            pt += __shfl_xor(pt, 2);
            pt += __shfl_xor(pt, 4);
            pt += __shfl_xor(pt, 8);
            part[e] = pt;
        }

        float m4 = fmaxf(fmaxf(part[0], part[1]), fmaxf(part[2], part[3]));
        if (__builtin_expect(m4 > mbase, 0)) {
            float sc = __expf(mbase - m4);
            lsum *= sc;
            #pragma unroll
            for (int q = 0; q < 8; ++q) acc[q] *= sc;
            mbase = m4;
        }
        float pw[4];
        #pragma unroll
        for (int e = 0; e < 4; ++e) pw[e] = __expf(part[e] - mbase);
        lsum += (pw[0] + pw[1]) + (pw[2] + pw[3]);

        #pragma unroll
        for (int e = 0; e < 4; ++e) {
            unsigned uw[8] = {curA[e].x, curA[e].y, curA[e].z, curA[e].w,
                              curB[e].x, curB[e].y, curB[e].z, curB[e].w};
            #pragma unroll
            for (int q = 0; q < 8; ++q)
                acc[q] += unpk2(uw[q]) * pw[e];
        }

        if (more) {
            #pragma unroll
            for (int i = 0; i < 4; ++i) { curA[i] = nxtA[i]; curB[i] = nxtB[i]; }
        }
    }

    for (int p = p0 + ngroups * 4; p < p1; ++p) {
        int s = colv[p];
        const unsigned short* src = xlr + (size_t)s * D2X2 + j0;
        uint4 a0 = *(const uint4*)src;
        uint4 a1 = *(const uint4*)(src + 8);
        unsigned uw[8] = {a0.x, a0.y, a0.z, a0.w, a1.x, a1.y, a1.z, a1.w};
        f32x2 d2 = (f32x2){0.f, 0.f};
        #pragma unroll
        for (int q = 0; q < 8; ++q) {
            f32x2 sv = unpk2(uw[q]) + xrv[q];
            f32x2 t = sv * 0.2f;
            sv.x = fmaxf(sv.x, t.x);
            sv.y = fmaxf(sv.y, t.y);
            d2 += sv * attv[q];
        }
        float pt = d2.x + d2.y;
        pt += __shfl_xor(pt, 1);
        pt += __shfl_xor(pt, 2);
        pt += __shfl_xor(pt, 4);
        pt += __shfl_xor(pt, 8);
        if (__builtin_expect(pt > mbase, 0)) {
            float sc = __expf(mbase - pt);
            lsum *= sc;
            #pragma unroll
            for (int q = 0; q < 8; ++q) acc[q] *= sc;
            mbase = pt;
        }
        float pw = __expf(pt - mbase);
        lsum += pw;
        #pragma unroll
        for (int q = 0; q < 8; ++q)
            acc[q] += unpk2(uw[q]) * pw;
    }

    float inv = 1.f / lsum;
    unsigned w[8];
    #pragma unroll
    for (int q = 0; q < 8; ++q) {
        float o0 = acc[q].x * inv + bias[j0 + 2 * q];
        float o1 = acc[q].y * inv + bias[j0 + 2 * q + 1];
        o0 = (o0 > 0.f) ? o0 : (__expf(o0) - 1.f);   // ELU
        o1 = (o1 > 0.f) ? o1 : (__expf(o1) - 1.f);
        w[q] = (unsigned)f2bf(o0) | ((unsigned)f2bf(o1) << 16);
    }
    uint4 v0, v1;
    v0.x = w[0]; v0.y = w[1]; v0.z = w[2]; v0.w = w[3];
    v1.x = w[4]; v1.y = w[5]; v1.z = w[6]; v1.w = w[7];
    *(uint4*)(out + (size_t)node * D2 + j0) = v0;
    *(uint4*)(out + (size_t)node * D2 + j0 + 8) = v1;
}

// ---------------- host launch ----------------
extern "C" void kernel_launch(void* const* d_in, const int* in_sizes, int n_in,
                              void* d_out, int out_size, void* d_ws, size_t ws_size,
                              hipStream_t stream) {
    const float* emb   = (const float*)d_in[0];
    const float* noise = (const float*)d_in[1];
    const int*   tarr  = (const int*)d_in[2];
    const int*   ei    = (const int*)d_in[3];
    const float* Wl1   = (const float*)d_in[4];
    const float* bl1   = (const float*)d_in[5];
    const float* Wr1   = (const float*)d_in[6];
    const float* br1   = (const float*)d_in[7];
    const float* att1  = (const float*)d_in[8];
    const float* bias1 = (const float*)d_in[9];
    const float* Wl2   = (const float*)d_in[10];
    const float* bl2   = (const float*)d_in[11];
    const float* Wr2   = (const float*)d_in[12];
    const float* br2   = (const float*)d_in[13];
    const float* att2  = (const float*)d_in[14];
    const float* bias2 = (const float*)d_in[15];
    const float* Wout  = (const float*)d_in[16];
    const float* bout  = (const float*)d_in[17];
    float* out = (float*)d_out;

    char* wsp = (char*)d_ws;
    size_t off = 0;
    auto carve = [&](size_t b) -> void* {
        void* p = wsp + off;
        off = (off + b + 255) & ~(size_t)255;
        return p;
    };
    float* sched = (float*)carve(128 * 4);
    int* cnt  = (int*)carve(NNODES * 4);
    int* rowp = (int*)carve((NNODES + 1) * 4);
    int* cur  = (int*)carve(NNODES * 4);
    int* colv = (int*)carve((NEDGES + NNODES) * 4);
    unsigned short* x0b   = (unsigned short*)carve((size_t)MPAD * FIN * 2);
    unsigned short* xlrb  = (unsigned short*)carve((size_t)MPAD * D2X2 * 2);
    unsigned short* hb    = (unsigned short*)carve((size_t)MPAD * D2 * 2);
    unsigned short* wlr1t = (unsigned short*)carve((size_t)FIN * D2X2 * 2);
    unsigned short* wlr2t = (unsigned short*)carve((size_t)D2 * D2X2 * 2);
    unsigned short* wot   = (unsigned short*)carve((size_t)D2 * FIN * 2);

    // allow 128 KB dynamic LDS on gemm8p (host-side, r3-proven path)
    hipFuncSetAttribute(reinterpret_cast<const void*>(gemm8p),
                        hipFuncAttributeMaxDynamicSharedMemorySize, LDSB);

    hipMemsetAsync(cnt, 0, NNODES * 4, stream);
    csr_count<<<(NEDGES + 255) / 256, 256, 0, stream>>>(ei, cnt);
    csr_scan<<<1, 1024, 0, stream>>>(cnt, rowp, cur, sched);
    csr_fill<<<(NEDGES + NNODES + 255) / 256, 256, 0, stream>>>(ei, rowp, cur, colv);

    // one kernel: 5 weight transposes
    {
        TJ5 js;
        js.j[0] = {Wl1,  wlr1t,                    FIN, D2,  768};
        js.j[1] = {Wr1,  wlr1t + (size_t)D2 * FIN, FIN, D2,  1536};
        js.j[2] = {Wl2,  wlr2t,                    D2,  D2,  2560};
        js.j[3] = {Wr2,  wlr2t + (size_t)D2 * D2,  D2,  D2,  3584};
        js.j[4] = {Wout, wot,                      D2,  FIN, 4352};
        prep_all<<<4352, 256, 0, stream>>>(js);
    }

    x0_kernel<<<(MPAD * (FIN / 4)) / 256, 256, 0, stream>>>(emb, noise, tarr, sched, x0b);

    // layer 1 fused GEMM: [MPAD x 768] @ [768 x 2048] -> xlrb   (40x8 = 320 blocks)
    gemm8p<<<dim3((MPAD / 256) * (D2X2 / 256)), 512, LDSB, stream>>>(
        x0b, wlr1t, bl1, br1, xlrb, FIN, D2X2, D2X2 / 256);
    attn_kernel<<<MPAD / 4, 256, 0, stream>>>(xlrb, rowp, colv, att1, bias1, hb);

    // layer 2 fused GEMM: [MPAD x 1024] @ [1024 x 2048] -> xlrb
    gemm8p<<<dim3((MPAD / 256) * (D2X2 / 256)), 512, LDSB, stream>>>(
        hb, wlr2t, bl2, br2, xlrb, D2, D2X2, D2X2 / 256);
    attn_kernel<<<MPAD / 4, 256, 0, stream>>>(xlrb, rowp, colv, att2, bias2, hb);

    // output GEMM: [MPAD x 1024] @ [1024 x 768] -> fp32 d_out (guarded rows; proven gemmM)
    gemmM<false><<<dim3((MPAD / 128) * (FIN / 128)), 256, 0, stream>>>(
        hb, wot, bout, bout, out, D2, FIN, NNODES, FIN / 128);

    (void)in_sizes; (void)n_in; (void)out_size; (void)ws_size;
}

// Round 12
// 335.021 us; speedup vs baseline: 1.1087x; 1.1087x over previous
//
#include <hip/hip_runtime.h>

#define NNODES 10000
#define NEDGES 160000
#define MPAD   10240      // 80 * 128
#define FIN    768
#define D2     1024
#define D2X2   2048
#define TSTEPS 50

typedef __bf16 bf16x8 __attribute__((ext_vector_type(8)));
typedef float  f32x4  __attribute__((ext_vector_type(4)));
typedef float  f32x2  __attribute__((ext_vector_type(2)));

__device__ __forceinline__ unsigned short f2bf(float f) {
    unsigned u = __builtin_bit_cast(unsigned, f);
    u += 0x7FFFu + ((u >> 16) & 1u);
    return (unsigned short)(u >> 16);
}
__device__ __forceinline__ f32x2 unpk2(unsigned u) {
    f32x2 r;
    r.x = __builtin_bit_cast(float, u << 16);
    r.y = __builtin_bit_cast(float, u & 0xFFFF0000u);
    return r;
}
__device__ __forceinline__ void gload16(const void* g, void* l) {
    __builtin_amdgcn_global_load_lds((const __attribute__((address_space(1))) void*)g,
                                     (__attribute__((address_space(3))) void*)l, 16, 0, 0);
}

// ---------------- CSR: count ----------------
__global__ void csr_count(const int* __restrict__ ei, int* cnt) {
    int g = blockIdx.x * 256 + threadIdx.x;
    if (g < NEDGES) atomicAdd(&cnt[ei[NEDGES + g]], 1);
}
// ---------------- CSR: scan (+ cosine schedule fold-in) ----------------
__global__ void csr_scan(const int* __restrict__ cnt, int* rowp, int* cur, float* sched) {
    if (threadIdx.x == 0) {
        const double PI = 3.14159265358979323846;
        double acp = 1.0;
        for (int i = 0; i < TSTEPS; ++i) {
            double x0 = (double)i / (double)TSTEPS;
            double x1 = (double)(i + 1) / (double)TSTEPS;
            double c0 = cos((x0 + 0.008) / 1.008 * PI * 0.5);
            double c1 = cos((x1 + 0.008) / 1.008 * PI * 0.5);
            double a0 = c0 * c0, a1 = c1 * c1;
            double beta = 1.0 - a1 / a0;
            if (beta < 0.0) beta = 0.0;
            if (beta > 0.999) beta = 0.999;
            acp *= (1.0 - beta);
            sched[i]      = (float)sqrt(acp);
            sched[64 + i] = (float)sqrt(1.0 - acp);
        }
    }
    __shared__ int part[1024];
    int tid = threadIdx.x;
    const int per = 10;
    int base = tid * per;
    int local[per];
    int s = 0;
    #pragma unroll
    for (int i = 0; i < per; ++i) {
        int idx = base + i;
        int v = (idx < NNODES) ? (cnt[idx] + 1) : 0;   // +1 = self loop
        local[i] = s;
        s += v;
    }
    part[tid] = s;
    __syncthreads();
    for (int off = 1; off < 1024; off <<= 1) {
        int v = (tid >= off) ? part[tid - off] : 0;
        __syncthreads();
        part[tid] += v;
        __syncthreads();
    }
    int offset = (tid > 0) ? part[tid - 1] : 0;
    #pragma unroll
    for (int i = 0; i < per; ++i) {
        int idx = base + i;
        if (idx < NNODES) {
            int v = offset + local[i];
            rowp[idx] = v;
            cur[idx]  = v;
        } else if (idx == NNODES) {
            rowp[NNODES] = offset + local[i];
        }
    }
}
// ---------------- CSR: fill (self loop at fixed last slot) ----------------
__global__ void csr_fill(const int* __restrict__ ei, const int* __restrict__ rowp,
                         int* cur, int* colv) {
    int g = blockIdx.x * 256 + threadIdx.x;
    if (g < NEDGES) {
        int s = ei[g];
        int d = ei[NEDGES + g];
        int pos = atomicAdd(&cur[d], 1);
        colv[pos] = s;
    } else if (g < NEDGES + NNODES) {
        int d = g - NEDGES;
        colv[rowp[d + 1] - 1] = d;
    }
}

// ---------------- unified weight transpose: 5 jobs, fp32 [K][N] -> bf16 [N][K] ----------------
struct TJ { const float* W; unsigned short* out; int K; int N; int end; };
struct TJ5 { TJ j[5]; };
__global__ void __launch_bounds__(256)
prep_all(TJ5 js) {
    int b = blockIdx.x;
    int i = 0;
    #pragma unroll
    for (int k = 0; k < 5; ++k) if (b >= js.j[k].end) i = k + 1;
    TJ p = js.j[i];
    int start = (i > 0) ? js.j[i - 1].end : 0;
    int lt = b - start;
    int kt = p.K >> 5;                 // tiles along K
    int kb = (lt % kt) * 32;
    int nb = (lt / kt) * 32;
    __shared__ float tile[32][33];
    const int tx = threadIdx.x & 31, ty = threadIdx.x >> 5;   // ty 0..7
    #pragma unroll
    for (int r = 0; r < 32; r += 8)
        tile[ty + r][tx] = p.W[(size_t)(kb + ty + r) * p.N + nb + tx];   // coalesced read
    __syncthreads();
    #pragma unroll
    for (int r = 0; r < 32; r += 8)
        p.out[(size_t)(nb + ty + r) * p.K + kb + tx] = f2bf(tile[tx][ty + r]);  // coalesced write
}

// ---------------- diffusion noise add -> bf16 ----------------
__global__ void x0_kernel(const float* __restrict__ emb, const float* __restrict__ noise,
                          const int* __restrict__ t, const float* __restrict__ sched,
                          unsigned short* __restrict__ x0b) {
    int i4 = blockIdx.x * 256 + threadIdx.x;
    if (i4 >= MPAD * (FIN / 4)) return;
    int row = i4 / (FIN / 4);
    int c = (i4 % (FIN / 4)) * 4;
    unsigned short* dst = x0b + (size_t)row * FIN + c;
    if (row < NNODES) {
        int tv = t[row];
        float sa = sched[tv], so = sched[64 + tv];
        float4 e = *(const float4*)(emb + (size_t)row * FIN + c);
        float4 nz = *(const float4*)(noise + (size_t)row * FIN + c);
        float v0 = sa * e.x + so * nz.x;
        float v1 = sa * e.y + so * nz.y;
        float v2 = sa * e.z + so * nz.z;
        float v3 = sa * e.w + so * nz.w;
        uint2 pk;
        pk.x = (unsigned)f2bf(v0) | ((unsigned)f2bf(v1) << 16);
        pk.y = (unsigned)f2bf(v2) | ((unsigned)f2bf(v3) << 16);
        *(uint2*)dst = pk;
    } else {
        uint2 pk; pk.x = 0u; pk.y = 0u;
        *(uint2*)dst = pk;
    }
}

// ---------------- m97-style bf16 MFMA GEMM (round-7/10 proven) ----------------
template<bool OUT_BF16>
__global__ void __launch_bounds__(256)
gemmM(const unsigned short* __restrict__ A, const unsigned short* __restrict__ Bt,
      const float* __restrict__ bl, const float* __restrict__ br, void* __restrict__ C,
      int K, int Nn, int Mstore, int gy) {
    __shared__ __align__(16) unsigned short As[128 * 64];   // 16 KB
    __shared__ __align__(16) unsigned short Bs[128 * 64];   // 16 KB

    const int tid = threadIdx.x;
    const int lane = tid & 63;
    const int wv = tid >> 6;          // 0..3
    const int wm = wv >> 1;           // 0..1
    const int wn = wv & 1;            // 0..1
    const int lr = lane & 15;
    const int kq = lane >> 4;

    // T1: bijective XCD swizzle (m204)
    const int total = gridDim.x;
    int lin = blockIdx.x;
    int q = total >> 3, r = total & 7;
    int xcd = lin & 7, idx = lin >> 3;
    int lin2 = (xcd < r ? xcd * (q + 1) : r * (q + 1) + (xcd - r) * q) + idx;
    const int rowBase = (lin2 / gy) * 128;
    const int colBase = (lin2 % gy) * 128;

    f32x4 acc[4][4];
    #pragma unroll
    for (int m = 0; m < 4; ++m)
        #pragma unroll
        for (int n = 0; n < 4; ++n)
            acc[m][n] = (f32x4){0.f, 0.f, 0.f, 0.f};

    const int r8 = tid >> 3;          // 0..31
    const int cb = (tid & 7) * 16;    // byte col in 128B row
    const size_t Kb = (size_t)K * 2;
    const int NT = K >> 6;

    for (int t = 0; t < NT; ++t) {
        const size_t kOff = (size_t)(t * 64) * 2;
        #pragma unroll
        for (int i = 0; i < 4; ++i) {
            int rr = i * 32 + r8;
            int scb = cb ^ ((rr & 7) << 4);     // inverse-swizzled global source
            gload16((const char*)A + (size_t)(rowBase + rr) * Kb + kOff + scb,
                    (char*)As + rr * 128 + cb);
            gload16((const char*)Bt + (size_t)(colBase + rr) * Kb + kOff + scb,
                    (char*)Bs + rr * 128 + cb);
        }
        __syncthreads();

        #pragma unroll
        for (int k2 = 0; k2 < 2; ++k2) {
            bf16x8 fa[4], fb[4];
            #pragma unroll
            for (int m = 0; m < 4; ++m) {
                int fr = wm * 64 + m * 16 + lr;
                int off = (fr * 128 + k2 * 64 + kq * 16) ^ ((fr & 7) << 4);  // T2 swizzled read
                fa[m] = *(const bf16x8*)((const char*)As + off);
            }
            #pragma unroll
            for (int n = 0; n < 4; ++n) {
                int fr = wn * 64 + n * 16 + lr;
                int off = (fr * 128 + k2 * 64 + kq * 16) ^ ((fr & 7) << 4);
                fb[n] = *(const bf16x8*)((const char*)Bs + off);
            }
            __builtin_amdgcn_s_setprio(1);
            #pragma unroll
            for (int m = 0; m < 4; ++m)
                #pragma unroll
                for (int n = 0; n < 4; ++n)
                    acc[m][n] = __builtin_amdgcn_mfma_f32_16x16x32_bf16(fa[m], fb[n], acc[m][n], 0, 0, 0);
            __builtin_amdgcn_s_setprio(0);
        }
        __syncthreads();
    }

    #pragma unroll
    for (int n = 0; n < 4; ++n) {
        int col = colBase + wn * 64 + n * 16 + lr;
        float bcol = (col < D2) ? bl[col] : br[col - D2];
        #pragma unroll
        for (int m = 0; m < 4; ++m) {
            int row0 = rowBase + wm * 64 + m * 16 + kq * 4;
            #pragma unroll
            for (int j = 0; j < 4; ++j) {
                float v = acc[m][n][j] + bcol;
                if (OUT_BF16) {
                    ((unsigned short*)C)[(size_t)(row0 + j) * Nn + col] = f2bf(v);
                } else {
                    if (row0 + j < Mstore)
                        ((float*)C)[(size_t)(row0 + j) * Nn + col] = v;
                }
            }
        }
    }
}

// ---------------- GATv2 attention: one wave per destination node (round-6/7/10 proven) ----------------
// 4-edge groups (independent under fixed softmax base), f32x2 packed math,
// 2-stage group prefetch. xlr: [MPAD][2048] bf16 (xl cols [0,1024), xr cols [1024,2048)).
__global__ void __launch_bounds__(256)
attn_kernel(const unsigned short* __restrict__ xlr,
            const int* __restrict__ rowp, const int* __restrict__ colv,
            const float* __restrict__ att, const float* __restrict__ bias,
            unsigned short* __restrict__ out) {
    const int lane = threadIdx.x & 63;
    const int node = blockIdx.x * 4 + (threadIdx.x >> 6);
    const int j0 = lane * 16;

    if (node >= NNODES) {
        if (node < MPAD) {
            uint4 z; z.x = z.y = z.z = z.w = 0u;
            *(uint4*)(out + (size_t)node * D2 + j0) = z;
            *(uint4*)(out + (size_t)node * D2 + j0 + 8) = z;
        }
        return;
    }

    f32x2 attv[8], xrv[8], acc[8];
    #pragma unroll
    for (int q = 0; q < 8; ++q) attv[q] = *(const f32x2*)(att + j0 + 2 * q);
    {
        const unsigned short* xr = xlr + (size_t)node * D2X2 + D2 + j0;
        uint4 v0 = *(const uint4*)(xr);
        uint4 v1 = *(const uint4*)(xr + 8);
        unsigned u[8] = {v0.x, v0.y, v0.z, v0.w, v1.x, v1.y, v1.z, v1.w};
        #pragma unroll
        for (int q = 0; q < 8; ++q) xrv[q] = unpk2(u[q]);
    }
    #pragma unroll
    for (int q = 0; q < 8; ++q) acc[q] = (f32x2){0.f, 0.f};

    float mbase = 8.0f;     // fixed softmax base; rescale fallback keeps exactness
    float lsum = 0.f;

    const int p0 = rowp[node], p1 = rowp[node + 1];
    const int deg = p1 - p0;
    const int ngroups = deg >> 2;

    uint4 curA[4], curB[4];
    if (ngroups > 0) {
        #pragma unroll
        for (int i = 0; i < 4; ++i) {
            int s = colv[p0 + i];
            const unsigned short* src = xlr + (size_t)s * D2X2 + j0;
            curA[i] = *(const uint4*)src;
            curB[i] = *(const uint4*)(src + 8);
        }
    }

    for (int g = 0; g < ngroups; ++g) {
        uint4 nxtA[4], nxtB[4];
        const bool more = (g + 1 < ngroups);
        if (more) {
            int base = p0 + (g + 1) * 4;
            #pragma unroll
            for (int i = 0; i < 4; ++i) {
                int s = colv[base + i];
                const unsigned short* src = xlr + (size_t)s * D2X2 + j0;
                nxtA[i] = *(const uint4*)src;
                nxtB[i] = *(const uint4*)(src + 8);
            }
        }

        float part[4];
        #pragma unroll
        for (int e = 0; e < 4; ++e) {
            unsigned uw[8] = {curA[e].x, curA[e].y, curA[e].z, curA[e].w,
                              curB[e].x, curB[e].y, curB[e].z, curB[e].w};
            f32x2 d2 = (f32x2){0.f, 0.f};
            #pragma unroll
            for (int q = 0; q < 8; ++q) {
                f32x2 s = unpk2(uw[q]) + xrv[q];
                f32x2 t = s * 0.2f;
                s.x = fmaxf(s.x, t.x);
                s.y = fmaxf(s.y, t.y);
                d2 += s * attv[q];
            }
            float pt = d2.x + d2.y;
            pt += __shfl_xor(pt, 1);
            pt += __shfl_xor(pt, 2);
            pt += __shfl_xor(pt, 4);
            pt += __shfl_xor(pt, 8);
            part[e] = pt;
        }

        float m4 = fmaxf(fmaxf(part[0], part[1]), fmaxf(part[2], part[3]));
        if (__builtin_expect(m4 > mbase, 0)) {
            float sc = __expf(mbase - m4);
            lsum *= sc;
            #pragma unroll
            for (int q = 0; q < 8; ++q) acc[q] *= sc;
            mbase = m4;
        }
        float pw[4];
        #pragma unroll
        for (int e = 0; e < 4; ++e) pw[e] = __expf(part[e] - mbase);
        lsum += (pw[0] + pw[1]) + (pw[2] + pw[3]);

        #pragma unroll
        for (int e = 0; e < 4; ++e) {
            unsigned uw[8] = {curA[e].x, curA[e].y, curA[e].z, curA[e].w,
                              curB[e].x, curB[e].y, curB[e].z, curB[e].w};
            #pragma unroll
            for (int q = 0; q < 8; ++q)
                acc[q] += unpk2(uw[q]) * pw[e];
        }

        if (more) {
            #pragma unroll
            for (int i = 0; i < 4; ++i) { curA[i] = nxtA[i]; curB[i] = nxtB[i]; }
        }
    }

    for (int p = p0 + ngroups * 4; p < p1; ++p) {
        int s = colv[p];
        const unsigned short* src = xlr + (size_t)s * D2X2 + j0;
        uint4 a0 = *(const uint4*)src;
        uint4 a1 = *(const uint4*)(src + 8);
        unsigned uw[8] = {a0.x, a0.y, a0.z, a0.w, a1.x, a1.y, a1.z, a1.w};
        f32x2 d2 = (f32x2){0.f, 0.f};
        #pragma unroll
        for (int q = 0; q < 8; ++q) {
            f32x2 sv = unpk2(uw[q]) + xrv[q];
            f32x2 t = sv * 0.2f;
            sv.x = fmaxf(sv.x, t.x);
            sv.y = fmaxf(sv.y, t.y);
            d2 += sv * attv[q];
        }
        float pt = d2.x + d2.y;
        pt += __shfl_xor(pt, 1);
        pt += __shfl_xor(pt, 2);
        pt += __shfl_xor(pt, 4);
        pt += __shfl_xor(pt, 8);
        if (__builtin_expect(pt > mbase, 0)) {
            float sc = __expf(mbase - pt);
            lsum *= sc;
            #pragma unroll
            for (int q = 0; q < 8; ++q) acc[q] *= sc;
            mbase = pt;
        }
        float pw = __expf(pt - mbase);
        lsum += pw;
        #pragma unroll
        for (int q = 0; q < 8; ++q)
            acc[q] += unpk2(uw[q]) * pw;
    }

    float inv = 1.f / lsum;
    unsigned w[8];
    #pragma unroll
    for (int q = 0; q < 8; ++q) {
        float o0 = acc[q].x * inv + bias[j0 + 2 * q];
        float o1 = acc[q].y * inv + bias[j0 + 2 * q + 1];
        o0 = (o0 > 0.f) ? o0 : (__expf(o0) - 1.f);   // ELU
        o1 = (o1 > 0.f) ? o1 : (__expf(o1) - 1.f);
        w[q] = (unsigned)f2bf(o0) | ((unsigned)f2bf(o1) << 16);
    }
    uint4 v0, v1;
    v0.x = w[0]; v0.y = w[1]; v0.z = w[2]; v0.w = w[3];
    v1.x = w[4]; v1.y = w[5]; v1.z = w[6]; v1.w = w[7];
    *(uint4*)(out + (size_t)node * D2 + j0) = v0;
    *(uint4*)(out + (size_t)node * D2 + j0 + 8) = v1;
}

// ---------------- host launch ----------------
extern "C" void kernel_launch(void* const* d_in, const int* in_sizes, int n_in,
                              void* d_out, int out_size, void* d_ws, size_t ws_size,
                              hipStream_t stream) {
    const float* emb   = (const float*)d_in[0];
    const float* noise = (const float*)d_in[1];
    const int*   tarr  = (const int*)d_in[2];
    const int*   ei    = (const int*)d_in[3];
    const float* Wl1   = (const float*)d_in[4];
    const float* bl1   = (const float*)d_in[5];
    const float* Wr1   = (const float*)d_in[6];
    const float* br1   = (const float*)d_in[7];
    const float* att1  = (const float*)d_in[8];
    const float* bias1 = (const float*)d_in[9];
    const float* Wl2   = (const float*)d_in[10];
    const float* bl2   = (const float*)d_in[11];
    const float* Wr2   = (const float*)d_in[12];
    const float* br2   = (const float*)d_in[13];
    const float* att2  = (const float*)d_in[14];
    const float* bias2 = (const float*)d_in[15];
    const float* Wout  = (const float*)d_in[16];
    const float* bout  = (const float*)d_in[17];
    float* out = (float*)d_out;

    char* wsp = (char*)d_ws;
    size_t off = 0;
    auto carve = [&](size_t b) -> void* {
        void* p = wsp + off;
        off = (off + b + 255) & ~(size_t)255;
        return p;
    };
    float* sched = (float*)carve(128 * 4);
    int* cnt  = (int*)carve(NNODES * 4);
    int* rowp = (int*)carve((NNODES + 1) * 4);
    int* cur  = (int*)carve(NNODES * 4);
    int* colv = (int*)carve((NEDGES + NNODES) * 4);
    unsigned short* x0b   = (unsigned short*)carve((size_t)MPAD * FIN * 2);
    unsigned short* xlrb  = (unsigned short*)carve((size_t)MPAD * D2X2 * 2);
    unsigned short* hb    = (unsigned short*)carve((size_t)MPAD * D2 * 2);
    unsigned short* wlr1t = (unsigned short*)carve((size_t)FIN * D2X2 * 2);
    unsigned short* wlr2t = (unsigned short*)carve((size_t)D2 * D2X2 * 2);
    unsigned short* wot   = (unsigned short*)carve((size_t)D2 * FIN * 2);

    hipMemsetAsync(cnt, 0, NNODES * 4, stream);
    csr_count<<<(NEDGES + 255) / 256, 256, 0, stream>>>(ei, cnt);
    csr_scan<<<1, 1024, 0, stream>>>(cnt, rowp, cur, sched);
    csr_fill<<<(NEDGES + NNODES + 255) / 256, 256, 0, stream>>>(ei, rowp, cur, colv);

    // one kernel: 5 weight transposes
    {
        TJ5 js;
        js.j[0] = {Wl1,  wlr1t,                    FIN, D2,  768};
        js.j[1] = {Wr1,  wlr1t + (size_t)D2 * FIN, FIN, D2,  1536};
        js.j[2] = {Wl2,  wlr2t,                    D2,  D2,  2560};
        js.j[3] = {Wr2,  wlr2t + (size_t)D2 * D2,  D2,  D2,  3584};
        js.j[4] = {Wout, wot,                      D2,  FIN, 4352};
        prep_all<<<4352, 256, 0, stream>>>(js);
    }

    x0_kernel<<<(MPAD * (FIN / 4)) / 256, 256, 0, stream>>>(emb, noise, tarr, sched, x0b);

    // layer 1 fused GEMM: [MPAD x 768] @ [768 x 2048] -> xlrb
    gemmM<true><<<dim3((MPAD / 128) * (D2X2 / 128)), 256, 0, stream>>>(
        x0b, wlr1t, bl1, br1, xlrb, FIN, D2X2, MPAD, D2X2 / 128);
    attn_kernel<<<MPAD / 4, 256, 0, stream>>>(xlrb, rowp, colv, att1, bias1, hb);

    // layer 2 fused GEMM: [MPAD x 1024] @ [1024 x 2048] -> xlrb
    gemmM<true><<<dim3((MPAD / 128) * (D2X2 / 128)), 256, 0, stream>>>(
        hb, wlr2t, bl2, br2, xlrb, D2, D2X2, MPAD, D2X2 / 128);
    attn_kernel<<<MPAD / 4, 256, 0, stream>>>(xlrb, rowp, colv, att2, bias2, hb);

    // output GEMM: [MPAD x 1024] @ [1024 x 768] -> fp32 d_out (guarded rows)
    gemmM<false><<<dim3((MPAD / 128) * (FIN / 128)), 256, 0, stream>>>(
        hb, wot, bout, bout, out, D2, FIN, NNODES, FIN / 128);

    (void)in_sizes; (void)n_in; (void)out_size; (void)ws_size;
}

// Round 13
// 328.202 us; speedup vs baseline: 1.1317x; 1.0208x over previous
//
#include <hip/hip_runtime.h>

#define NNODES 10000
#define NEDGES 160000
#define MPAD   10240      // 80 * 128
#define FIN    768
#define D2     1024
#define D2X2   2048
#define TSTEPS 50

#define NB_CNT  625       // (NEDGES+255)/256
#define NB_PREP 4352      // 5 transpose jobs
#define NB_X0   7680      // MPAD*(FIN/4)/256

typedef __bf16 bf16x8 __attribute__((ext_vector_type(8)));
typedef float  f32x4  __attribute__((ext_vector_type(4)));
typedef float  f32x2  __attribute__((ext_vector_type(2)));

__device__ __forceinline__ unsigned short f2bf(float f) {
    unsigned u = __builtin_bit_cast(unsigned, f);
    u += 0x7FFFu + ((u >> 16) & 1u);
    return (unsigned short)(u >> 16);
}
__device__ __forceinline__ f32x2 unpk2(unsigned u) {
    f32x2 r;
    r.x = __builtin_bit_cast(float, u << 16);
    r.y = __builtin_bit_cast(float, u & 0xFFFF0000u);
    return r;
}
__device__ __forceinline__ void gload16(const void* g, void* l) {
    __builtin_amdgcn_global_load_lds((const __attribute__((address_space(1))) void*)g,
                                     (__attribute__((address_space(3))) void*)l, 16, 0, 0);
}

struct TJ { const float* W; unsigned short* out; int K; int N; int end; };
struct TJ5 { TJ j[5]; };

// ---------------- sched0: cosine schedule + cnt zeroing (replaces memset dispatch) ----------------
__global__ void sched0(int* cnt, float* sched) {
    const int tid = threadIdx.x;
    for (int i = tid; i < NNODES; i += 256) cnt[i] = 0;
    if (tid == 0) {
        const double PI = 3.14159265358979323846;
        double acp = 1.0;
        for (int i = 0; i < TSTEPS; ++i) {
            double x0 = (double)i / (double)TSTEPS;
            double x1 = (double)(i + 1) / (double)TSTEPS;
            double c0 = cos((x0 + 0.008) / 1.008 * PI * 0.5);
            double c1 = cos((x1 + 0.008) / 1.008 * PI * 0.5);
            double a0 = c0 * c0, a1 = c1 * c1;
            double beta = 1.0 - a1 / a0;
            if (beta < 0.0) beta = 0.0;
            if (beta > 0.999) beta = 0.999;
            acp *= (1.0 - beta);
            sched[i]      = (float)sqrt(acp);
            sched[64 + i] = (float)sqrt(1.0 - acp);
        }
    }
}

// ---------------- fused_pre: csr_count + 5 weight transposes + x0 (independent jobs) ----------------
__global__ void __launch_bounds__(256)
fused_pre(const int* __restrict__ ei, int* cnt, TJ5 js,
          const float* __restrict__ emb, const float* __restrict__ noise,
          const int* __restrict__ t, const float* __restrict__ sched,
          unsigned short* __restrict__ x0b) {
    __shared__ float tile[32][33];
    int b = blockIdx.x;

    if (b < NB_CNT) {
        // ---- csr_count (proven body) ----
        int g = b * 256 + threadIdx.x;
        if (g < NEDGES) atomicAdd(&cnt[ei[NEDGES + g]], 1);
        return;
    }
    b -= NB_CNT;

    if (b < NB_PREP) {
        // ---- prep_all (proven body, blockIdx -> b) ----
        int i = 0;
        #pragma unroll
        for (int k = 0; k < 5; ++k) if (b >= js.j[k].end) i = k + 1;
        TJ p = js.j[i];
        int start = (i > 0) ? js.j[i - 1].end : 0;
        int lt = b - start;
        int kt = p.K >> 5;
        int kb = (lt % kt) * 32;
        int nb = (lt / kt) * 32;
        const int tx = threadIdx.x & 31, ty = threadIdx.x >> 5;
        #pragma unroll
        for (int r = 0; r < 32; r += 8)
            tile[ty + r][tx] = p.W[(size_t)(kb + ty + r) * p.N + nb + tx];
        __syncthreads();
        #pragma unroll
        for (int r = 0; r < 32; r += 8)
            p.out[(size_t)(nb + ty + r) * p.K + kb + tx] = f2bf(tile[tx][ty + r]);
        return;
    }
    b -= NB_PREP;

    // ---- x0 (proven body, blockIdx -> b) ----
    int i4 = b * 256 + threadIdx.x;
    if (i4 >= MPAD * (FIN / 4)) return;
    int row = i4 / (FIN / 4);
    int c = (i4 % (FIN / 4)) * 4;
    unsigned short* dst = x0b + (size_t)row * FIN + c;
    if (row < NNODES) {
        int tv = t[row];
        float sa = sched[tv], so = sched[64 + tv];
        float4 e = *(const float4*)(emb + (size_t)row * FIN + c);
        float4 nz = *(const float4*)(noise + (size_t)row * FIN + c);
        float v0 = sa * e.x + so * nz.x;
        float v1 = sa * e.y + so * nz.y;
        float v2 = sa * e.z + so * nz.z;
        float v3 = sa * e.w + so * nz.w;
        uint2 pk;
        pk.x = (unsigned)f2bf(v0) | ((unsigned)f2bf(v1) << 16);
        pk.y = (unsigned)f2bf(v2) | ((unsigned)f2bf(v3) << 16);
        *(uint2*)dst = pk;
    } else {
        uint2 pk; pk.x = 0u; pk.y = 0u;
        *(uint2*)dst = pk;
    }
}

// ---------------- CSR: scan (schedule moved to sched0) ----------------
__global__ void csr_scan(const int* __restrict__ cnt, int* rowp, int* cur) {
    __shared__ int part[1024];
    int tid = threadIdx.x;
    const int per = 10;
    int base = tid * per;
    int local[per];
    int s = 0;
    #pragma unroll
    for (int i = 0; i < per; ++i) {
        int idx = base + i;
        int v = (idx < NNODES) ? (cnt[idx] + 1) : 0;   // +1 = self loop
        local[i] = s;
        s += v;
    }
    part[tid] = s;
    __syncthreads();
    for (int off = 1; off < 1024; off <<= 1) {
        int v = (tid >= off) ? part[tid - off] : 0;
        __syncthreads();
        part[tid] += v;
        __syncthreads();
    }
    int offset = (tid > 0) ? part[tid - 1] : 0;
    #pragma unroll
    for (int i = 0; i < per; ++i) {
        int idx = base + i;
        if (idx < NNODES) {
            int v = offset + local[i];
            rowp[idx] = v;
            cur[idx]  = v;
        } else if (idx == NNODES) {
            rowp[NNODES] = offset + local[i];
        }
    }
}
// ---------------- CSR: fill (self loop at fixed last slot) ----------------
__global__ void csr_fill(const int* __restrict__ ei, const int* __restrict__ rowp,
                         int* cur, int* colv) {
    int g = blockIdx.x * 256 + threadIdx.x;
    if (g < NEDGES) {
        int s = ei[g];
        int d = ei[NEDGES + g];
        int pos = atomicAdd(&cur[d], 1);
        colv[pos] = s;
    } else if (g < NEDGES + NNODES) {
        int d = g - NEDGES;
        colv[rowp[d + 1] - 1] = d;
    }
}

// ---------------- m97-style bf16 MFMA GEMM (round-7/10/12 proven) ----------------
template<bool OUT_BF16>
__global__ void __launch_bounds__(256)
gemmM(const unsigned short* __restrict__ A, const unsigned short* __restrict__ Bt,
      const float* __restrict__ bl, const float* __restrict__ br, void* __restrict__ C,
      int K, int Nn, int Mstore, int gy) {
    __shared__ __align__(16) unsigned short As[128 * 64];   // 16 KB
    __shared__ __align__(16) unsigned short Bs[128 * 64];   // 16 KB

    const int tid = threadIdx.x;
    const int lane = tid & 63;
    const int wv = tid >> 6;          // 0..3
    const int wm = wv >> 1;           // 0..1
    const int wn = wv & 1;            // 0..1
    const int lr = lane & 15;
    const int kq = lane >> 4;

    // T1: bijective XCD swizzle (m204)
    const int total = gridDim.x;
    int lin = blockIdx.x;
    int q = total >> 3, r = total & 7;
    int xcd = lin & 7, idx = lin >> 3;
    int lin2 = (xcd < r ? xcd * (q + 1) : r * (q + 1) + (xcd - r) * q) + idx;
    const int rowBase = (lin2 / gy) * 128;
    const int colBase = (lin2 % gy) * 128;

    f32x4 acc[4][4];
    #pragma unroll
    for (int m = 0; m < 4; ++m)
        #pragma unroll
        for (int n = 0; n < 4; ++n)
            acc[m][n] = (f32x4){0.f, 0.f, 0.f, 0.f};

    const int r8 = tid >> 3;          // 0..31
    const int cb = (tid & 7) * 16;    // byte col in 128B row
    const size_t Kb = (size_t)K * 2;
    const int NT = K >> 6;

    for (int t = 0; t < NT; ++t) {
        const size_t kOff = (size_t)(t * 64) * 2;
        #pragma unroll
        for (int i = 0; i < 4; ++i) {
            int rr = i * 32 + r8;
            int scb = cb ^ ((rr & 7) << 4);     // inverse-swizzled global source
            gload16((const char*)A + (size_t)(rowBase + rr) * Kb + kOff + scb,
                    (char*)As + rr * 128 + cb);
            gload16((const char*)Bt + (size_t)(colBase + rr) * Kb + kOff + scb,
                    (char*)Bs + rr * 128 + cb);
        }
        __syncthreads();

        #pragma unroll
        for (int k2 = 0; k2 < 2; ++k2) {
            bf16x8 fa[4], fb[4];
            #pragma unroll
            for (int m = 0; m < 4; ++m) {
                int fr = wm * 64 + m * 16 + lr;
                int off = (fr * 128 + k2 * 64 + kq * 16) ^ ((fr & 7) << 4);  // T2 swizzled read
                fa[m] = *(const bf16x8*)((const char*)As + off);
            }
            #pragma unroll
            for (int n = 0; n < 4; ++n) {
                int fr = wn * 64 + n * 16 + lr;
                int off = (fr * 128 + k2 * 64 + kq * 16) ^ ((fr & 7) << 4);
                fb[n] = *(const bf16x8*)((const char*)Bs + off);
            }
            __builtin_amdgcn_s_setprio(1);
            #pragma unroll
            for (int m = 0; m < 4; ++m)
                #pragma unroll
                for (int n = 0; n < 4; ++n)
                    acc[m][n] = __builtin_amdgcn_mfma_f32_16x16x32_bf16(fa[m], fb[n], acc[m][n], 0, 0, 0);
            __builtin_amdgcn_s_setprio(0);
        }
        __syncthreads();
    }

    #pragma unroll
    for (int n = 0; n < 4; ++n) {
        int col = colBase + wn * 64 + n * 16 + lr;
        float bcol = (col < D2) ? bl[col] : br[col - D2];
        #pragma unroll
        for (int m = 0; m < 4; ++m) {
            int row0 = rowBase + wm * 64 + m * 16 + kq * 4;
            #pragma unroll
            for (int j = 0; j < 4; ++j) {
                float v = acc[m][n][j] + bcol;
                if (OUT_BF16) {
                    ((unsigned short*)C)[(size_t)(row0 + j) * Nn + col] = f2bf(v);
                } else {
                    if (row0 + j < Mstore)
                        ((float*)C)[(size_t)(row0 + j) * Nn + col] = v;
                }
            }
        }
    }
}

// ---------------- GATv2 attention: one wave per destination node (round-6/7/10/12 proven) ----------------
__global__ void __launch_bounds__(256)
attn_kernel(const unsigned short* __restrict__ xlr,
            const int* __restrict__ rowp, const int* __restrict__ colv,
            const float* __restrict__ att, const float* __restrict__ bias,
            unsigned short* __restrict__ out) {
    const int lane = threadIdx.x & 63;
    const int node = blockIdx.x * 4 + (threadIdx.x >> 6);
    const int j0 = lane * 16;

    if (node >= NNODES) {
        if (node < MPAD) {
            uint4 z; z.x = z.y = z.z = z.w = 0u;
            *(uint4*)(out + (size_t)node * D2 + j0) = z;
            *(uint4*)(out + (size_t)node * D2 + j0 + 8) = z;
        }
        return;
    }

    f32x2 attv[8], xrv[8], acc[8];
    #pragma unroll
    for (int q = 0; q < 8; ++q) attv[q] = *(const f32x2*)(att + j0 + 2 * q);
    {
        const unsigned short* xr = xlr + (size_t)node * D2X2 + D2 + j0;
        uint4 v0 = *(const uint4*)(xr);
        uint4 v1 = *(const uint4*)(xr + 8);
        unsigned u[8] = {v0.x, v0.y, v0.z, v0.w, v1.x, v1.y, v1.z, v1.w};
        #pragma unroll
        for (int q = 0; q < 8; ++q) xrv[q] = unpk2(u[q]);
    }
    #pragma unroll
    for (int q = 0; q < 8; ++q) acc[q] = (f32x2){0.f, 0.f};

    float mbase = 8.0f;     // fixed softmax base; rescale fallback keeps exactness
    float lsum = 0.f;

    const int p0 = rowp[node], p1 = rowp[node + 1];
    const int deg = p1 - p0;
    const int ngroups = deg >> 2;

    uint4 curA[4], curB[4];
    if (ngroups > 0) {
        #pragma unroll
        for (int i = 0; i < 4; ++i) {
            int s = colv[p0 + i];
            const unsigned short* src = xlr + (size_t)s * D2X2 + j0;
            curA[i] = *(const uint4*)src;
            curB[i] = *(const uint4*)(src + 8);
        }
    }

    for (int g = 0; g < ngroups; ++g) {
        uint4 nxtA[4], nxtB[4];
        const bool more = (g + 1 < ngroups);
        if (more) {
            int base = p0 + (g + 1) * 4;
            #pragma unroll
            for (int i = 0; i < 4; ++i) {
                int s = colv[base + i];
                const unsigned short* src = xlr + (size_t)s * D2X2 + j0;
                nxtA[i] = *(const uint4*)src;
                nxtB[i] = *(const uint4*)(src + 8);
            }
        }

        float part[4];
        #pragma unroll
        for (int e = 0; e < 4; ++e) {
            unsigned uw[8] = {curA[e].x, curA[e].y, curA[e].z, curA[e].w,
                              curB[e].x, curB[e].y, curB[e].z, curB[e].w};
            f32x2 d2 = (f32x2){0.f, 0.f};
            #pragma unroll
            for (int q = 0; q < 8; ++q) {
                f32x2 s = unpk2(uw[q]) + xrv[q];
                f32x2 t = s * 0.2f;
                s.x = fmaxf(s.x, t.x);
                s.y = fmaxf(s.y, t.y);
                d2 += s * attv[q];
            }
            float pt = d2.x + d2.y;
            pt += __shfl_xor(pt, 1);
            pt += __shfl_xor(pt, 2);
            pt += __shfl_xor(pt, 4);
            pt += __shfl_xor(pt, 8);
            part[e] = pt;
        }

        float m4 = fmaxf(fmaxf(part[0], part[1]), fmaxf(part[2], part[3]));
        if (__builtin_expect(m4 > mbase, 0)) {
            float sc = __expf(mbase - m4);
            lsum *= sc;
            #pragma unroll
            for (int q = 0; q < 8; ++q) acc[q] *= sc;
            mbase = m4;
        }
        float pw[4];
        #pragma unroll
        for (int e = 0; e < 4; ++e) pw[e] = __expf(part[e] - mbase);
        lsum += (pw[0] + pw[1]) + (pw[2] + pw[3]);

        #pragma unroll
        for (int e = 0; e < 4; ++e) {
            unsigned uw[8] = {curA[e].x, curA[e].y, curA[e].z, curA[e].w,
                              curB[e].x, curB[e].y, curB[e].z, curB[e].w};
            #pragma unroll
            for (int q = 0; q < 8; ++q)
                acc[q] += unpk2(uw[q]) * pw[e];
        }

        if (more) {
            #pragma unroll
            for (int i = 0; i < 4; ++i) { curA[i] = nxtA[i]; curB[i] = nxtB[i]; }
        }
    }

    for (int p = p0 + ngroups * 4; p < p1; ++p) {
        int s = colv[p];
        const unsigned short* src = xlr + (size_t)s * D2X2 + j0;
        uint4 a0 = *(const uint4*)src;
        uint4 a1 = *(const uint4*)(src + 8);
        unsigned uw[8] = {a0.x, a0.y, a0.z, a0.w, a1.x, a1.y, a1.z, a1.w};
        f32x2 d2 = (f32x2){0.f, 0.f};
        #pragma unroll
        for (int q = 0; q < 8; ++q) {
            f32x2 sv = unpk2(uw[q]) + xrv[q];
            f32x2 t = sv * 0.2f;
            sv.x = fmaxf(sv.x, t.x);
            sv.y = fmaxf(sv.y, t.y);
            d2 += sv * attv[q];
        }
        float pt = d2.x + d2.y;
        pt += __shfl_xor(pt, 1);
        pt += __shfl_xor(pt, 2);
        pt += __shfl_xor(pt, 4);
        pt += __shfl_xor(pt, 8);
        if (__builtin_expect(pt > mbase, 0)) {
            float sc = __expf(mbase - pt);
            lsum *= sc;
            #pragma unroll
            for (int q = 0; q < 8; ++q) acc[q] *= sc;
            mbase = pt;
        }
        float pw = __expf(pt - mbase);
        lsum += pw;
        #pragma unroll
        for (int q = 0; q < 8; ++q)
            acc[q] += unpk2(uw[q]) * pw;
    }

    float inv = 1.f / lsum;
    unsigned w[8];
    #pragma unroll
    for (int q = 0; q < 8; ++q) {
        float o0 = acc[q].x * inv + bias[j0 + 2 * q];
        float o1 = acc[q].y * inv + bias[j0 + 2 * q + 1];
        o0 = (o0 > 0.f) ? o0 : (__expf(o0) - 1.f);   // ELU
        o1 = (o1 > 0.f) ? o1 : (__expf(o1) - 1.f);
        w[q] = (unsigned)f2bf(o0) | ((unsigned)f2bf(o1) << 16);
    }
    uint4 v0, v1;
    v0.x = w[0]; v0.y = w[1]; v0.z = w[2]; v0.w = w[3];
    v1.x = w[4]; v1.y = w[5]; v1.z = w[6]; v1.w = w[7];
    *(uint4*)(out + (size_t)node * D2 + j0) = v0;
    *(uint4*)(out + (size_t)node * D2 + j0 + 8) = v1;
}

// ---------------- host launch ----------------
extern "C" void kernel_launch(void* const* d_in, const int* in_sizes, int n_in,
                              void* d_out, int out_size, void* d_ws, size_t ws_size,
                              hipStream_t stream) {
    const float* emb   = (const float*)d_in[0];
    const float* noise = (const float*)d_in[1];
    const int*   tarr  = (const int*)d_in[2];
    const int*   ei    = (const int*)d_in[3];
    const float* Wl1   = (const float*)d_in[4];
    const float* bl1   = (const float*)d_in[5];
    const float* Wr1   = (const float*)d_in[6];
    const float* br1   = (const float*)d_in[7];
    const float* att1  = (const float*)d_in[8];
    const float* bias1 = (const float*)d_in[9];
    const float* Wl2   = (const float*)d_in[10];
    const float* bl2   = (const float*)d_in[11];
    const float* Wr2   = (const float*)d_in[12];
    const float* br2   = (const float*)d_in[13];
    const float* att2  = (const float*)d_in[14];
    const float* bias2 = (const float*)d_in[15];
    const float* Wout  = (const float*)d_in[16];
    const float* bout  = (const float*)d_in[17];
    float* out = (float*)d_out;

    char* wsp = (char*)d_ws;
    size_t off = 0;
    auto carve = [&](size_t b) -> void* {
        void* p = wsp + off;
        off = (off + b + 255) & ~(size_t)255;
        return p;
    };
    float* sched = (float*)carve(128 * 4);
    int* cnt  = (int*)carve(NNODES * 4);
    int* rowp = (int*)carve((NNODES + 1) * 4);
    int* cur  = (int*)carve(NNODES * 4);
    int* colv = (int*)carve((NEDGES + NNODES) * 4);
    unsigned short* x0b   = (unsigned short*)carve((size_t)MPAD * FIN * 2);
    unsigned short* xlrb  = (unsigned short*)carve((size_t)MPAD * D2X2 * 2);
    unsigned short* hb    = (unsigned short*)carve((size_t)MPAD * D2 * 2);
    unsigned short* wlr1t = (unsigned short*)carve((size_t)FIN * D2X2 * 2);
    unsigned short* wlr2t = (unsigned short*)carve((size_t)D2 * D2X2 * 2);
    unsigned short* wot   = (unsigned short*)carve((size_t)D2 * FIN * 2);

    // 1) schedule + cnt zeroing (1 block)
    sched0<<<1, 256, 0, stream>>>(cnt, sched);

    // 2) fused pre-pass: csr_count + 5 weight transposes + x0 (independent jobs)
    {
        TJ5 js;
        js.j[0] = {Wl1,  wlr1t,                    FIN, D2,  768};
        js.j[1] = {Wr1,  wlr1t + (size_t)D2 * FIN, FIN, D2,  1536};
        js.j[2] = {Wl2,  wlr2t,                    D2,  D2,  2560};
        js.j[3] = {Wr2,  wlr2t + (size_t)D2 * D2,  D2,  D2,  3584};
        js.j[4] = {Wout, wot,                      D2,  FIN, 4352};
        fused_pre<<<NB_CNT + NB_PREP + NB_X0, 256, 0, stream>>>(
            ei, cnt, js, emb, noise, tarr, sched, x0b);
    }

    // 3) CSR scan + fill
    csr_scan<<<1, 1024, 0, stream>>>(cnt, rowp, cur);
    csr_fill<<<(NEDGES + NNODES + 255) / 256, 256, 0, stream>>>(ei, rowp, cur, colv);

    // layer 1 fused GEMM: [MPAD x 768] @ [768 x 2048] -> xlrb
    gemmM<true><<<dim3((MPAD / 128) * (D2X2 / 128)), 256, 0, stream>>>(
        x0b, wlr1t, bl1, br1, xlrb, FIN, D2X2, MPAD, D2X2 / 128);
    attn_kernel<<<MPAD / 4, 256, 0, stream>>>(xlrb, rowp, colv, att1, bias1, hb);

    // layer 2 fused GEMM: [MPAD x 1024] @ [1024 x 2048] -> xlrb
    gemmM<true><<<dim3((MPAD / 128) * (D2X2 / 128)), 256, 0, stream>>>(
        hb, wlr2t, bl2, br2, xlrb, D2, D2X2, MPAD, D2X2 / 128);
    attn_kernel<<<MPAD / 4, 256, 0, stream>>>(xlrb, rowp, colv, att2, bias2, hb);

    // output GEMM: [MPAD x 1024] @ [1024 x 768] -> fp32 d_out (guarded rows)
    gemmM<false><<<dim3((MPAD / 128) * (FIN / 128)), 256, 0, stream>>>(
        hb, wot, bout, bout, out, D2, FIN, NNODES, FIN / 128);

    (void)in_sizes; (void)n_in; (void)out_size; (void)ws_size;
}